// Round 3
// baseline (91.214 us; speedup 1.0000x reference)
//
#include <hip/hip_runtime.h>

// x (N,S,C,V) = (8,2048,4,64) fp32; embedding (C,K,V) = (4,512,64) fp32.
#define NROW 16384   // N*S
#define CCH  4
#define KCB  512
#define VDIM 64

typedef __attribute__((ext_vector_type(8))) short  short8;   // 8 x bf16
typedef __attribute__((ext_vector_type(4))) float  floatx4;  // MFMA acc

// round-to-nearest-even fp32 -> bf16 bits; rem = v - bf16(v)
__device__ inline unsigned short bf16h(float v, float* rem) {
    unsigned u = __float_as_uint(v);
    unsigned r = u + 0x7FFFu + ((u >> 16) & 1u);
    unsigned short h = (unsigned short)(r >> 16);
    *rem = v - __uint_as_float((unsigned)h << 16);
    return h;
}
__device__ inline unsigned short bf16r(float v) {   // RNE round only
    unsigned u = __float_as_uint(v);
    return (unsigned short)((u + 0x7FFFu + ((u >> 16) & 1u)) >> 16);
}
__device__ inline float bf16f(short v) {            // bf16 bits -> fp32
    return __uint_as_float(((unsigned)(unsigned short)v) << 16);
}

// Epilogue for 16 rows owned by this wave's row-group: out0 = emb[code]
// (ref's (e-x)+x == e to <1e-6), out1/out2 from x_hat = hi+lo reconstruction
// (|x-x_hat| <= |x|*2^-17 -> out1 err ~1e-2 worst, << accepted flip band).
__device__ __forceinline__ void epi_rows(
    short8 h0, short8 h1, short8 l0, short8 l1,
    int rl, int row, int c, int quad,
    const float* __restrict__ embc, const float* pkm,
    float* __restrict__ out)
{
    const float pmin = fminf(pkm[rl * 2], pkm[rl * 2 + 1]);
    const int  code  = (int)(__float_as_uint(pmin) & 511u);
    const float4* er = (const float4*)(embc + (size_t)code * VDIM);
    float4* wr = (float4*)(out + ((size_t)row * CCH + c) * VDIM);

    const float4 e00 = er[quad * 2],     e01 = er[quad * 2 + 1];
    const float4 e10 = er[8 + quad * 2], e11 = er[8 + quad * 2 + 1];
    wr[quad * 2]     = e00;  wr[quad * 2 + 1]     = e01;
    wr[8 + quad * 2] = e10;  wr[8 + quad * 2 + 1] = e11;

    const float ea0[8] = {e00.x, e00.y, e00.z, e00.w, e01.x, e01.y, e01.z, e01.w};
    const float ea1[8] = {e10.x, e10.y, e10.z, e10.w, e11.x, e11.y, e11.z, e11.w};
    float s = 0.f;
#pragma unroll
    for (int j = 0; j < 8; ++j) {
        const float d0 = (bf16f(h0[j]) + bf16f(l0[j])) - ea0[j];
        s = fmaf(d0, d0, s);
        const float d1 = (bf16f(h1[j]) + bf16f(l1[j])) - ea1[j];
        s = fmaf(d1, d1, s);
    }
    s += __shfl_xor(s, 16, 64);
    s += __shfl_xor(s, 32, 64);
    if (quad == 0) {
        const size_t base1 = (size_t)NROW * CCH * VDIM;
        const size_t base2 = base1 + (size_t)NROW * CCH;
        const size_t idx = (size_t)row * CCH + c;
        out[base1 + idx] = s;                // out1
        out[base2 + idx] = s;                // out2 (identical in ref)
    }
}

// Block = 512 thr (8 waves); grid = (NROW/128, CCH) = 512 blocks = 2/CU.
// LDS = eh (64 KB) + e2 (2 KB) + pkm (1 KB merge buf) = 67.5 KB -> 2 blocks/CU.
//
// SPLIT-K: waves 0-3 scan codes [0,256) over rows [0,128); waves 4-7 scan
// codes [256,512). Merge through pkm + 1 barrier. (Measured NEUTRAL vs the
// non-split baseline -- K-loop is not the critical path; kept because it
// also halves per-wave K-loop work and enables the rg-split epilogue.)
//
// EPILOGUE FROM REGISTERS (this round's change): no global x re-read.
// Each row's x lives in the owning wave's ah/al fragments; wave kh
// epilogues row-group rg==kh (uniform branch, no runtime frag indexing).
// Removes 16.8 MB of cold-HBM reads + a dependent load chain per row.
//
// Packed argmin: pk = min(pk, asfloat((asuint(d) & ~511) | code)); 9 cleared
// mantissa bits perturb d by <~2e-3, inside the accepted bf16-noise band.
// LDS layout eh[(koct*512 + (code ^ koct))*8 + j]: XOR swizzle keeps both
// staging writes and fragment reads bank-conflict-free.
__global__ __launch_bounds__(512, 4)
void vq_fused(const float* __restrict__ x, const float* __restrict__ emb,
              float* __restrict__ out) {
    extern __shared__ unsigned short smem[];
    unsigned short* eh = smem;              // 32768 ushorts = 64 KB
    float* e2s = (float*)(smem + 32768);    // 512 floats = 2 KB
    float* pkm = e2s + KCB;                 // 128 rows x 2 halves = 1 KB

    const int tid  = threadIdx.x;
    const int lane = tid & 63;
    const int m    = lane & 15;
    const int quad = lane >> 4;
    const int wave = tid >> 6;
    const int c    = blockIdx.y;
    const int blockRow = blockIdx.x * 128;

    const float* embc = emb + (size_t)c * (KCB * VDIM);

    // --- stage codebook: wave covers 64 codes; 16 coalesced 1KB wave-reads ---
    {
        const int cb = wave * 64;
        const int koct = m >> 1, half = m & 1;
#pragma unroll
        for (int j = 0; j < 16; ++j) {
            const int g = cb * 16 + j * 64 + lane;       // float4 index
            const float4 t = ((const float4*)embc)[g];
            const int code = cb + j * 4 + quad;          // this lane's code
            ushort4 h4;
            h4.x = bf16r(t.x); h4.y = bf16r(t.y);
            h4.z = bf16r(t.z); h4.w = bf16r(t.w);
            const int off = (koct * 512 + (code ^ koct)) * 8 + half * 4;
            *(ushort4*)&eh[off] = h4;
            // fused exact-fp32 e2: reduce over the 16 lanes of this code
            float s = 0.f;
            s = fmaf(t.x, t.x, s); s = fmaf(t.y, t.y, s);
            s = fmaf(t.z, t.z, s); s = fmaf(t.w, t.w, s);
            s += __shfl_xor(s, 1, 64);
            s += __shfl_xor(s, 2, 64);
            s += __shfl_xor(s, 4, 64);
            s += __shfl_xor(s, 8, 64);
            if (m == 0) e2s[code] = s;
        }
    }

    // --- A fragments: 2 row-groups (32 rows) per wave, 2 k-halves, x hi/lo ---
    const int kh  = wave >> 2;                 // split-K half (code half)
    const int rb2 = blockRow + (wave & 3) * 32;
    short8 ah[2][2], al[2][2];                 // [row-group][k-half]
#pragma unroll
    for (int rg = 0; rg < 2; ++rg) {
        const int row = rb2 + rg * 16 + m;
        const float4* xr = (const float4*)(x + ((size_t)row * CCH + c) * VDIM);
#pragma unroll
        for (int h = 0; h < 2; ++h) {          // k = h*32 + quad*8 + j
            const float4 f0 = xr[h * 8 + quad * 2];
            const float4 f1 = xr[h * 8 + quad * 2 + 1];
            const float fv[8] = {f0.x, f0.y, f0.z, f0.w, f1.x, f1.y, f1.z, f1.w};
            short8 hh, ll;
#pragma unroll
            for (int j = 0; j < 8; ++j) {
                float r, d;
                hh[j] = (short)bf16h(fv[j], &r);
                ll[j] = (short)bf16h(r, &d);
            }
            ah[rg][h] = hh; al[rg][h] = ll;
        }
    }

    __syncthreads();   // barrier 1: eh/e2s ready

    float pk0[4], pk1[4];                      // packed (d,code) per row-group
#pragma unroll
    for (int j = 0; j < 4; ++j) {
        pk0[j] = __uint_as_float(0x7F7FFFFFu);
        pk1[j] = __uint_as_float(0x7F7FFFFFu);
    }

    const int mq0 = m ^ quad;                  // swizzled read indices
    const int mq1 = m ^ (quad + 4);
    const int codeLane = kh * 256 + m;

#pragma unroll 2
    for (int t = 0; t < 16; ++t) {             // 16 tiles (this wave's half)
        const int tt = kh * 16 + t;
        const short8 bh0 = *(const short8*)&eh[( quad      * 512 + tt * 16 + mq0) * 8];
        const short8 bh1 = *(const short8*)&eh[((quad + 4) * 512 + tt * 16 + mq1) * 8];
        const float e2v = e2s[tt * 16 + m];
        const int  code = codeLane + t * 16;   // == tt*16 + m

        // two independent depth-4 chains: acc = (xh + xl) . e per row-group
        floatx4 a0 = {0.f,0.f,0.f,0.f}, a1 = {0.f,0.f,0.f,0.f};
        a0 = __builtin_amdgcn_mfma_f32_16x16x32_bf16(ah[0][0], bh0, a0, 0, 0, 0);
        a1 = __builtin_amdgcn_mfma_f32_16x16x32_bf16(ah[1][0], bh0, a1, 0, 0, 0);
        a0 = __builtin_amdgcn_mfma_f32_16x16x32_bf16(al[0][0], bh0, a0, 0, 0, 0);
        a1 = __builtin_amdgcn_mfma_f32_16x16x32_bf16(al[1][0], bh0, a1, 0, 0, 0);
        a0 = __builtin_amdgcn_mfma_f32_16x16x32_bf16(ah[0][1], bh1, a0, 0, 0, 0);
        a1 = __builtin_amdgcn_mfma_f32_16x16x32_bf16(ah[1][1], bh1, a1, 0, 0, 0);
        a0 = __builtin_amdgcn_mfma_f32_16x16x32_bf16(al[0][1], bh1, a0, 0, 0, 0);
        a1 = __builtin_amdgcn_mfma_f32_16x16x32_bf16(al[1][1], bh1, a1, 0, 0, 0);

#pragma unroll
        for (int j = 0; j < 4; ++j) {
            const float d0 = fmaf(-2.0f, a0[j], e2v);
            pk0[j] = fminf(pk0[j],
                __uint_as_float((__float_as_uint(d0) & 0xFFFFFE00u) | code));
            const float d1 = fmaf(-2.0f, a1[j], e2v);
            pk1[j] = fminf(pk1[j],
                __uint_as_float((__float_as_uint(d1) & 0xFFFFFE00u) | code));
        }
    }

    // within-quad (16-lane) argmin on packed values
#pragma unroll
    for (int j = 0; j < 4; ++j) {
#pragma unroll
        for (int mask = 1; mask < 16; mask <<= 1) {
            pk0[j] = fminf(pk0[j], __shfl_xor(pk0[j], mask, 64));
            pk1[j] = fminf(pk1[j], __shfl_xor(pk1[j], mask, 64));
        }
    }

    // publish per-row winners of this code-half
    {
        const int rloc = (wave & 3) * 32;
#pragma unroll
        for (int j = 0; j < 4; ++j) {
            if (m == j) {
                pkm[(rloc + quad * 4 + j) * 2 + kh]      = pk0[j];
                pkm[(rloc + 16 + quad * 4 + j) * 2 + kh] = pk1[j];
            }
        }
    }

    __syncthreads();   // barrier 2: pkm ready

    // Epilogue: wave kh handles its row-group rg==kh (16 rows), all data
    // from registers + L2-hot emb. No global x re-read.
    {
        const int rl0 = (wave & 3) * 32 + m;           // rg = 0 local row
        if (kh == 0)
            epi_rows(ah[0][0], ah[0][1], al[0][0], al[0][1],
                     rl0, blockRow + rl0, c, quad, embc, pkm, out);
        else
            epi_rows(ah[1][0], ah[1][1], al[1][0], al[1][1],
                     rl0 + 16, blockRow + rl0 + 16, c, quad, embc, pkm, out);
    }
}

extern "C" void kernel_launch(void* const* d_in, const int* in_sizes, int n_in,
                              void* d_out, int out_size, void* d_ws, size_t ws_size,
                              hipStream_t stream) {
    const float* x   = (const float*)d_in[0];
    const float* emb = (const float*)d_in[1];
    float* out = (float*)d_out;
    const size_t lds_bytes = 65536u + 2048u + 1024u;   // 68608 B -> 2 blocks/CU
    vq_fused<<<dim3(NROW / 128, CCH), dim3(512), lds_bytes, stream>>>(x, emb, out);
}

// Round 4
// 86.466 us; speedup vs baseline: 1.0549x; 1.0549x over previous
//
#include <hip/hip_runtime.h>

// x (N,S,C,V) = (8,2048,4,64) fp32; embedding (C,K,V) = (4,512,64) fp32.
#define NROW 16384   // N*S
#define CCH  4
#define KCB  512
#define VDIM 64

typedef __attribute__((ext_vector_type(8))) short  short8;   // 8 x bf16 / 16B
typedef __attribute__((ext_vector_type(4))) float  floatx4;  // MFMA acc

// round-to-nearest-even fp32 -> bf16 bits; rem = v - bf16(v)
__device__ inline unsigned short bf16h(float v, float* rem) {
    unsigned u = __float_as_uint(v);
    unsigned r = u + 0x7FFFu + ((u >> 16) & 1u);
    unsigned short h = (unsigned short)(r >> 16);
    *rem = v - __uint_as_float((unsigned)h << 16);
    return h;
}
__device__ inline unsigned short bf16r(float v) {   // RNE round only
    unsigned u = __float_as_uint(v);
    return (unsigned short)((u + 0x7FFFu + ((u >> 16) & 1u)) >> 16);
}

// ---------------------------------------------------------------------------
// Precompute (4 blocks x 512 thr): bf16 codebook in the EXACT eh-swizzled
// LDS layout + exact fp32 e2, into workspace. Runs once; removes per-block
// convert + shuffle-reduce staging work from all 512 main blocks.
// ws layout: [c*32768 .. +32768) ushorts  = swizzled bf16 codebook (64 KB/ch)
//            [4*32768 ..]                 = fp32 e2[c][512]  (8 KB)
// Element v (0..63) of code k:  idx = (v>>3)*4096 + ((k^(v>>3))<<3)
//                                     + ((v>>2)&1)*4 + (v&3)
// (identical to the in-kernel staging formula with m = v>>2).
// ---------------------------------------------------------------------------
__global__ __launch_bounds__(512)
void vq_precomp(const float* __restrict__ emb, unsigned short* __restrict__ ws) {
    const int c = blockIdx.x;          // channel
    const int k = threadIdx.x;         // code
    const float* er = emb + ((size_t)c * KCB + k) * VDIM;
    unsigned short* wc = ws + (size_t)c * 32768;
    float s = 0.f;
#pragma unroll
    for (int q = 0; q < 16; ++q) {     // float4 q = elements 4q..4q+3
        const float4 t = ((const float4*)er)[q];
        ushort4 h4;
        h4.x = bf16r(t.x); h4.y = bf16r(t.y);
        h4.z = bf16r(t.z); h4.w = bf16r(t.w);
        const int koct = q >> 1, half = q & 1;
        *(ushort4*)&wc[(koct * 512 + (k ^ koct)) * 8 + half * 4] = h4;
        s = fmaf(t.x, t.x, s); s = fmaf(t.y, t.y, s);
        s = fmaf(t.z, t.z, s); s = fmaf(t.w, t.w, s);
    }
    ((float*)(ws + 4 * 32768))[c * 512 + k] = s;   // exact fp32 e2
}

// Block = 512 thr (8 waves); grid = (NROW/128, CCH) = 512 blocks = 2/CU.
// LDS = eh (64 KB) + e2 (2 KB) + pkm (1 KB merge buf) = 67.5 KB -> 2 blocks/CU.
//
// SPLIT-K: waves 0-3 scan codes [0,256) over rows [0,128); waves 4-7 scan
// codes [256,512). Merge through pkm + 1 barrier. (Measured NEUTRAL vs
// non-split; kept — it halves per-wave K-loop work at no cost.)
//
// MODE 1 (workspace available): staging = 8 coalesced short8 copies +
// 8 ds_write_b128 + 1 e2 float copy per thread. No converts, no shuffle
// reduce, half the staged bytes. MODE 0: original in-kernel staging.
//
// Epilogue: R2-measured form (global x re-read — L3-hot, full-line out0
// writes). Register epilogue measured -6us REGRESSION in R3; reverted.
//
// Packed argmin: pk = min(pk, asfloat((asuint(d) & ~511) | code)); 9 cleared
// mantissa bits perturb d by <~2e-3, inside the accepted bf16-noise band.
// LDS layout eh[(koct*512 + (code ^ koct))*8 + j]: XOR swizzle keeps both
// staging writes and fragment reads bank-conflict-free.
template <int MODE>
__global__ __launch_bounds__(512, 4)
void vq_fused(const float* __restrict__ x, const float* __restrict__ emb,
              const unsigned short* __restrict__ ws, float* __restrict__ out) {
    extern __shared__ unsigned short smem[];
    unsigned short* eh = smem;              // 32768 ushorts = 64 KB
    float* e2s = (float*)(smem + 32768);    // 512 floats = 2 KB
    float* pkm = e2s + KCB;                 // 128 rows x 2 halves = 1 KB

    const int tid  = threadIdx.x;
    const int lane = tid & 63;
    const int m    = lane & 15;
    const int quad = lane >> 4;
    const int wave = tid >> 6;
    const int c    = blockIdx.y;
    const int blockRow = blockIdx.x * 128;

    const float* embc = emb + (size_t)c * (KCB * VDIM);

    if constexpr (MODE == 1) {
        // --- stage pre-swizzled bf16 codebook: pure copy, fully coalesced ---
        const short8* wsrc = (const short8*)(ws + (size_t)c * 32768);
#pragma unroll
        for (int r = 0; r < 8; ++r)
            *(short8*)&eh[(r * 512 + tid) * 8] = wsrc[r * 512 + tid];
        e2s[tid] = ((const float*)(ws + 4 * 32768))[c * 512 + tid];
    } else {
        // --- in-kernel staging: wave covers 64 codes; 16 coalesced reads ---
        const int cb = wave * 64;
        const int koct = m >> 1, half = m & 1;
#pragma unroll
        for (int j = 0; j < 16; ++j) {
            const int g = cb * 16 + j * 64 + lane;       // float4 index
            const float4 t = ((const float4*)embc)[g];
            const int code = cb + j * 4 + quad;          // this lane's code
            ushort4 h4;
            h4.x = bf16r(t.x); h4.y = bf16r(t.y);
            h4.z = bf16r(t.z); h4.w = bf16r(t.w);
            const int off = (koct * 512 + (code ^ koct)) * 8 + half * 4;
            *(ushort4*)&eh[off] = h4;
            float s = 0.f;
            s = fmaf(t.x, t.x, s); s = fmaf(t.y, t.y, s);
            s = fmaf(t.z, t.z, s); s = fmaf(t.w, t.w, s);
            s += __shfl_xor(s, 1, 64);
            s += __shfl_xor(s, 2, 64);
            s += __shfl_xor(s, 4, 64);
            s += __shfl_xor(s, 8, 64);
            if (m == 0) e2s[code] = s;
        }
    }

    // --- A fragments: 2 row-groups (32 rows) per wave, 2 k-halves, x hi/lo ---
    const int kh  = wave >> 2;                 // split-K half (code half)
    const int rb2 = blockRow + (wave & 3) * 32;
    short8 ah[2][2], al[2][2];                 // [row-group][k-half]
#pragma unroll
    for (int rg = 0; rg < 2; ++rg) {
        const int row = rb2 + rg * 16 + m;
        const float4* xr = (const float4*)(x + ((size_t)row * CCH + c) * VDIM);
#pragma unroll
        for (int h = 0; h < 2; ++h) {          // k = h*32 + quad*8 + j
            const float4 f0 = xr[h * 8 + quad * 2];
            const float4 f1 = xr[h * 8 + quad * 2 + 1];
            const float fv[8] = {f0.x, f0.y, f0.z, f0.w, f1.x, f1.y, f1.z, f1.w};
            short8 hh, ll;
#pragma unroll
            for (int j = 0; j < 8; ++j) {
                float r, d;
                hh[j] = (short)bf16h(fv[j], &r);
                ll[j] = (short)bf16h(r, &d);
            }
            ah[rg][h] = hh; al[rg][h] = ll;
        }
    }

    __syncthreads();   // barrier 1: eh/e2s ready

    float pk0[4], pk1[4];                      // packed (d,code) per row-group
#pragma unroll
    for (int j = 0; j < 4; ++j) {
        pk0[j] = __uint_as_float(0x7F7FFFFFu);
        pk1[j] = __uint_as_float(0x7F7FFFFFu);
    }

    const int mq0 = m ^ quad;                  // swizzled read indices
    const int mq1 = m ^ (quad + 4);
    const int codeLane = kh * 256 + m;

#pragma unroll 2
    for (int t = 0; t < 16; ++t) {             // 16 tiles (this wave's half)
        const int tt = kh * 16 + t;
        const short8 bh0 = *(const short8*)&eh[( quad      * 512 + tt * 16 + mq0) * 8];
        const short8 bh1 = *(const short8*)&eh[((quad + 4) * 512 + tt * 16 + mq1) * 8];
        const float e2v = e2s[tt * 16 + m];
        const int  code = codeLane + t * 16;   // == tt*16 + m

        // two independent depth-4 chains: acc = (xh + xl) . e per row-group
        floatx4 a0 = {0.f,0.f,0.f,0.f}, a1 = {0.f,0.f,0.f,0.f};
        a0 = __builtin_amdgcn_mfma_f32_16x16x32_bf16(ah[0][0], bh0, a0, 0, 0, 0);
        a1 = __builtin_amdgcn_mfma_f32_16x16x32_bf16(ah[1][0], bh0, a1, 0, 0, 0);
        a0 = __builtin_amdgcn_mfma_f32_16x16x32_bf16(al[0][0], bh0, a0, 0, 0, 0);
        a1 = __builtin_amdgcn_mfma_f32_16x16x32_bf16(al[1][0], bh0, a1, 0, 0, 0);
        a0 = __builtin_amdgcn_mfma_f32_16x16x32_bf16(ah[0][1], bh1, a0, 0, 0, 0);
        a1 = __builtin_amdgcn_mfma_f32_16x16x32_bf16(ah[1][1], bh1, a1, 0, 0, 0);
        a0 = __builtin_amdgcn_mfma_f32_16x16x32_bf16(al[0][1], bh1, a0, 0, 0, 0);
        a1 = __builtin_amdgcn_mfma_f32_16x16x32_bf16(al[1][1], bh1, a1, 0, 0, 0);

#pragma unroll
        for (int j = 0; j < 4; ++j) {
            const float d0 = fmaf(-2.0f, a0[j], e2v);
            pk0[j] = fminf(pk0[j],
                __uint_as_float((__float_as_uint(d0) & 0xFFFFFE00u) | code));
            const float d1 = fmaf(-2.0f, a1[j], e2v);
            pk1[j] = fminf(pk1[j],
                __uint_as_float((__float_as_uint(d1) & 0xFFFFFE00u) | code));
        }
    }

    // within-quad (16-lane) argmin on packed values
#pragma unroll
    for (int j = 0; j < 4; ++j) {
#pragma unroll
        for (int mask = 1; mask < 16; mask <<= 1) {
            pk0[j] = fminf(pk0[j], __shfl_xor(pk0[j], mask, 64));
            pk1[j] = fminf(pk1[j], __shfl_xor(pk1[j], mask, 64));
        }
    }

    // publish per-row winners of this code-half
    {
        const int rloc = (wave & 3) * 32;
#pragma unroll
        for (int j = 0; j < 4; ++j) {
            if (m == j) {
                pkm[(rloc + quad * 4 + j) * 2 + kh]      = pk0[j];
                pkm[(rloc + 16 + quad * 4 + j) * 2 + kh] = pk1[j];
            }
        }
    }

    __syncthreads();   // barrier 2: pkm ready

    // Epilogue (R2-measured form): wave handles 16 rows; exact fp32 from
    // original x (L3-hot re-read) and emb; full-line coalesced out0 writes.
    const size_t base1 = (size_t)NROW * CCH * VDIM;
    const size_t base2 = base1 + (size_t)NROW * CCH;
#pragma unroll
    for (int j = 0; j < 4; ++j) {
        const int rl   = wave * 16 + quad * 4 + j;
        const float pmin = fminf(pkm[rl * 2], pkm[rl * 2 + 1]);
        const int  code  = (int)(__float_as_uint(pmin) & 511u);  // uniform in quad
        const int  row   = blockRow + rl;
        const float4 t4 = ((const float4*)(x + ((size_t)row * CCH + c) * VDIM))[m];
        const float4 e4 = ((const float4*)(embc + (size_t)code * VDIM))[m];
        float4 w;
        w.x = (e4.x - t4.x) + t4.x;              // out0 = (output - x) + x
        w.y = (e4.y - t4.y) + t4.y;
        w.z = (e4.z - t4.z) + t4.z;
        w.w = (e4.w - t4.w) + t4.w;
        ((float4*)(out + ((size_t)row * CCH + c) * VDIM))[m] = w;
        float s = 0.f, dx;
        dx = t4.x - e4.x; s = fmaf(dx, dx, s);
        dx = t4.y - e4.y; s = fmaf(dx, dx, s);
        dx = t4.z - e4.z; s = fmaf(dx, dx, s);
        dx = t4.w - e4.w; s = fmaf(dx, dx, s);
        s += __shfl_xor(s, 1, 64);
        s += __shfl_xor(s, 2, 64);
        s += __shfl_xor(s, 4, 64);
        s += __shfl_xor(s, 8, 64);
        if (m == 0) {
            const size_t idx = (size_t)row * CCH + c;
            out[base1 + idx] = s;                // out1
            out[base2 + idx] = s;                // out2 (identical in ref)
        }
    }
}

extern "C" void kernel_launch(void* const* d_in, const int* in_sizes, int n_in,
                              void* d_out, int out_size, void* d_ws, size_t ws_size,
                              hipStream_t stream) {
    const float* x   = (const float*)d_in[0];
    const float* emb = (const float*)d_in[1];
    float* out = (float*)d_out;
    const size_t lds_bytes = 65536u + 2048u + 1024u;   // 68608 B -> 2 blocks/CU
    const size_t ws_need = 4u * 32768u * 2u + 4u * 512u * 4u;  // 270336 B
    if (d_ws != nullptr && ws_size >= ws_need) {
        unsigned short* ws = (unsigned short*)d_ws;
        vq_precomp<<<dim3(CCH), dim3(512), 0, stream>>>(emb, ws);
        vq_fused<1><<<dim3(NROW / 128, CCH), dim3(512), lds_bytes, stream>>>(
            x, emb, ws, out);
    } else {
        vq_fused<0><<<dim3(NROW / 128, CCH), dim3(512), lds_bytes, stream>>>(
            x, emb, nullptr, out);
    }
}